// Round 25
// baseline (181.303 us; speedup 1.0000x reference)
//
#include <hip/hip_runtime.h>
#include <stdint.h>
#include <math.h>

typedef __bf16 bf16;
typedef float f32x4 __attribute__((ext_vector_type(4)));
typedef int   i32x4 __attribute__((ext_vector_type(4)));

#define B_DIM 8192
#define K_DIM 4096
#define N_DIM 4096
#define MEM_H 1048576
#define HMOD  1047552   // MEM_H - 32*32
#define NT    (K_DIM / 64)

// ---------------- host-side numpy legacy RNG replication ----------------
static void mt_randint3(uint32_t seed, long long R[3]) {
  uint32_t mt[624];
  mt[0] = seed;
  for (int i = 1; i < 624; i++)
    mt[i] = 1812433253u * (mt[i - 1] ^ (mt[i - 1] >> 30)) + (uint32_t)i;
  int pos = 624;
  auto next32 = [&]() -> uint32_t {
    if (pos >= 624) {
      for (int i = 0; i < 624; i++) {
        uint32_t y = (mt[i] & 0x80000000u) | (mt[(i + 1) % 624] & 0x7fffffffu);
        uint32_t v = mt[(i + 397) % 624] ^ (y >> 1);
        if (y & 1u) v ^= 0x9908b0dfu;
        mt[i] = v;
      }
      pos = 0;
    }
    uint32_t y = mt[pos++];
    y ^= y >> 11;
    y ^= (y << 7) & 0x9d2c5680u;
    y ^= (y << 15) & 0xefc60000u;
    y ^= y >> 18;
    return y;
  };
  for (int j = 0; j < 3; j++) {
    uint32_t v;
    do { v = next32() & 0x7fffffffu; } while (v > 0x7ffffffdu);
    R[j] = 1LL + (long long)v;
  }
}

// ---------------- f32 -> int8 (scale 32, RTN, clamp +-127) --------------
__device__ __forceinline__ uint32_t q8(float v) {
  int q = (int)rintf(v * 32.0f);
  q = q > 127 ? 127 : (q < -127 ? -127 : q);
  return (uint32_t)(q & 0xFF);
}

// -------- prep: quantize x (natural) AND build W fragment-major ---------
// W-build fully coalesced via LDS bounce (R23).
__global__ void k_prep(const float* __restrict__ x, uint8_t* __restrict__ xq,
                       const float* __restrict__ hw, uint8_t* __restrict__ wq,
                       long long R1, long long R2, long long R3) {
  __shared__ uint32_t ls32[256];
  if (blockIdx.x < 8192) {
    int id = blockIdx.x * 256 + threadIdx.x;     // 16 consecutive floats
    const float* base = x + (size_t)id * 16;
    uint32_t r[4];
#pragma unroll
    for (int j = 0; j < 4; j++) {
      f32x4 v = *(const f32x4*)(base + j * 4);
      r[j] = q8(v[0]) | (q8(v[1]) << 8) | (q8(v[2]) << 16) | (q8(v[3]) << 24);
    }
    ((uint4*)xq)[id] = make_uint4(r[0], r[1], r[2], r[3]);
  } else {
    int tile = blockIdx.x - 8192;
    int kb = tile & 127, nb = tile >> 7;
    long long v = (long long)kb * R3 + (long long)nb * R2 + R1;
    int start = (int)((v % 2147483647LL) % (long long)HMOD);
    const float* src = hw + start;
    uint8_t* ls = (uint8_t*)ls32;
    int t = threadIdx.x;
    int r = t >> 3;                 // k-local row
    int c0 = (4 * t) & 31;          // n-local col of first element
    f32x4 vv = *(const f32x4*)(src + r * 32 + c0);   // coalesced 16B
#pragma unroll
    for (int j = 0; j < 4; j++) {
      int c = c0 + j;
      int off = ((c >> 4) << 9) + (((c & 15) + ((r >> 4) << 4)) << 4) + (r & 15);
      ls[off] = (uint8_t)q8(vv[j] * 64.0f);
    }
    __syncthreads();
    int h = t >> 7, i4 = t & 127;
    uint32_t word = ls32[(h << 7) + i4];
    size_t seg = ((size_t)((nb * 2 + h) * 64 + (kb >> 1)) << 10) +
                 ((size_t)(kb & 1) << 9);
    *(uint32_t*)(wq + seg + i4 * 4) = word;
  }
}

// ---- 256x256 int8 GEMM: A via LDS, B global->regs depth-2, 1 BAR/tile --
// FINAL (R23 structure). Plateau notes: seven schedule variants (4/2/1
// barriers, B-prefetch depth 1/2, TLP splits) all land 127-129 us.
// acc[8][4] = 128 regs of the UNIFIED VGPR/AGPR file -> combined ~252
// regs/wave -> 2 waves/SIMD is a hard floor; a second co-resident block
// requires halving acc (doubles B traffic; measured regression, R18).
// Ledger (FIFO, B-loads & A-DMA share vmcnt):
//   P1-top outstanding = {B(t+1)x4, A(t+1)x2, B(t+2)x4} = 10
//   VMC(4) drains B(t+1)+A(t+1); BAR; STAGE A(t+2) -> 6; P0 issues -> 10.
// (vmcnt is per-wave: counted wait must sit BEFORE its barrier.)
__device__ __forceinline__ void gload_lds16(const void* g, void* l) {
  __builtin_amdgcn_global_load_lds(
      (const __attribute__((address_space(1))) void*)g,
      (__attribute__((address_space(3))) void*)l, 16, 0, 0);
}

#define SGB() __builtin_amdgcn_sched_barrier(0)
#define VMC(n)  do { SGB(); asm volatile("s_waitcnt vmcnt(" #n ")"); SGB(); } while (0)
#define LGKM(n) do { SGB(); asm volatile("s_waitcnt lgkmcnt(" #n ")"); SGB(); } while (0)
#define BAR() __builtin_amdgcn_s_barrier()
#define DSR128(dst, base, off) \
  asm volatile("ds_read_b128 %0, %1 offset:" off : "=&v"(dst) : "v"(base))
#define GLB128(dst, ptr) \
  asm volatile("global_load_dwordx4 %0, %1, off" : "=&v"(dst) : "v"(ptr))

#define FM(RH, R4, CB, AF, BG)                                                 \
  acc[(RH)*4 + (R4)][CB] = __builtin_amdgcn_mfma_i32_16x16x64_i8(              \
      AF[R4], BG[CB], acc[(RH)*4 + (R4)][CB], 0, 0, 0)
#define FM8(RH, C0, C1, AF, BG) do {                                           \
  FM(RH, 0, C0, AF, BG); FM(RH, 1, C0, AF, BG);                                \
  FM(RH, 2, C0, AF, BG); FM(RH, 3, C0, AF, BG);                                \
  FM(RH, 0, C1, AF, BG); FM(RH, 1, C1, AF, BG);                                \
  FM(RH, 2, C1, AF, BG); FM(RH, 3, C1, AF, BG); } while (0)

// One K=64 tile. BGC = B regs for this tile (ready); BGN2 <- B(t+2).
#define TILE(T, BGC, BGN2) do {                                                \
  int t2c = ((T) + 2 < NT) ? (T) + 2 : NT - 1;                                 \
  int cur = (T) & 1;                                                           \
  uint32_t bsel = (uint32_t)cur << 14;                                         \
  uint32_t Ac = aA + bsel, An = aA + (16384u - bsel);                          \
  /* P0: MFMA(afE x BGC); mid: read afO(cur), issue B(t+2) */                  \
  LGKM(0);                                                                     \
  __builtin_amdgcn_s_setprio(1);                                               \
  FM8(0, 0, 1, afE, BGC);                                                      \
  SGB();                                                                       \
  DSR128(afO[0], Ac, "4096"); DSR128(afO[1], Ac, "5120");                      \
  DSR128(afO[2], Ac, "6144"); DSR128(afO[3], Ac, "7168");                      \
  GLB128(BGN2[0], Bw + t2c * 1024);                                            \
  GLB128(BGN2[1], Bw + 65536 + t2c * 1024);                                    \
  GLB128(BGN2[2], Bw + 131072 + t2c * 1024);                                   \
  GLB128(BGN2[3], Bw + 196608 + t2c * 1024);                                   \
  SGB();                                                                       \
  FM8(0, 2, 3, afE, BGC);                                                      \
  __builtin_amdgcn_s_setprio(0);                                               \
  /* P1: gate afO; VMC(4); BAR; STAGE A(t+2); MFMA; mid afE(nxt) */            \
  LGKM(0);                                                                     \
  VMC(4);                                                                      \
  BAR();                                                                       \
  STAGE_A(0, t2c, cur); STAGE_A(1, t2c, cur);                                  \
  __builtin_amdgcn_s_setprio(1);                                               \
  FM8(1, 0, 1, afO, BGC);                                                      \
  SGB();                                                                       \
  DSR128(afE[0], An, "0");    DSR128(afE[1], An, "1024");                      \
  DSR128(afE[2], An, "2048"); DSR128(afE[3], An, "3072");                      \
  SGB();                                                                       \
  FM8(1, 2, 3, afO, BGC);                                                      \
  __builtin_amdgcn_s_setprio(0);                                               \
} while (0)

__global__ __launch_bounds__(512, 2) void k_gemm(const uint8_t* __restrict__ Aq,
                                                 const uint8_t* __restrict__ Bq,
                                                 float* __restrict__ partial) {
  // A only: [buf][16 units x 1KB] : 32 KiB
  __shared__ uint8_t smq[2][16384];
  int bid = blockIdx.x;
  int swz = (bid & 7) * 64 + (bid >> 3);     // 512 blocks, 8 XCDs, bijective
  int mt = swz & 31, nt = swz >> 5;
  int tid = threadIdx.x;
  int w = tid >> 6, lane = tid & 63;
  int wm = w >> 2, wn = w & 3;               // 2 x 4 wave grid, 128x64 each
  int lr = lane & 15, lk = lane >> 4;
  size_t bm = (size_t)mt * 256;
  const uint8_t* Ab = Aq + (bm << 12);
  // B fragment-major: wave's col-block cb -> frag base (nt*16 + wn*4 + cb)*64
  const uint8_t* Bw = Bq + ((size_t)(nt * 16 + wn * 4) << 16) + lane * 16;

  i32x4 acc[8][4] = {};
  i32x4 afE[4], afO[4], bgA[4], bgB[4], bgC[4], bgD[4];

  auto STAGE_A = [&](int h, int tt, int buf) {
    gload_lds16(Ab + ((size_t)(h * 128 + w * 16 + lr) << 12) + tt * 64 + lk * 16,
                &smq[buf][(h * 8 + w) * 1024]);
  };

  uint32_t smb = (uint32_t)(uintptr_t)
      (__attribute__((address_space(3))) uint8_t*)&smq[0][0];
  uint32_t aA = smb + wm * 8192 + lane * 16;

  // prologue (steady FIFO order): B(0)x4, A(0)x2, B(1)x4, A(1)x2;
  // VMC(6) drains B(0)+A(0), leaves {B(1),A(1)}=6; BAR; pre-read afE(0).
  GLB128(bgA[0], Bw);
  GLB128(bgA[1], Bw + 65536);
  GLB128(bgA[2], Bw + 131072);
  GLB128(bgA[3], Bw + 196608);
  STAGE_A(0, 0, 0); STAGE_A(1, 0, 0);
  GLB128(bgB[0], Bw + 1024);
  GLB128(bgB[1], Bw + 65536 + 1024);
  GLB128(bgB[2], Bw + 131072 + 1024);
  GLB128(bgB[3], Bw + 196608 + 1024);
  STAGE_A(0, 1, 1); STAGE_A(1, 1, 1);
  VMC(6);
  BAR();
  DSR128(afE[0], aA, "0");    DSR128(afE[1], aA, "1024");
  DSR128(afE[2], aA, "2048"); DSR128(afE[3], aA, "3072");

  for (int tq = 0; tq < NT / 4; tq++) {
    TILE(4 * tq,     bgA, bgC);
    TILE(4 * tq + 1, bgB, bgD);
    TILE(4 * tq + 2, bgC, bgA);
    TILE(4 * tq + 3, bgD, bgB);
  }
  VMC(0);
  LGKM(0);   // drain tail DMA/loads/reads before epilogue

  // epilogue: per-row sum of squares over this wave's 64 cols
  // C frag: col = cb*16 + (lane&15), row = rb*16 + (lane>>4)*4 + reg
#pragma unroll
  for (int rb = 0; rb < 8; rb++) {
#pragma unroll
    for (int reg = 0; reg < 4; reg++) {
      float s = 0.f;
#pragma unroll
      for (int cb = 0; cb < 4; cb++) {
        float v = (float)acc[rb][cb][reg];
        s += v * v;
      }
      s += __shfl_xor(s, 1);
      s += __shfl_xor(s, 2);
      s += __shfl_xor(s, 4);
      s += __shfl_xor(s, 8);
      if (lr == 0) {
        int row = (int)bm + wm * 128 + rb * 16 + lk * 4 + reg;
        partial[(size_t)(nt * 4 + wn) * B_DIM + row] = s;
      }
    }
  }
}

// ---- finish: sum 64 partials, sqrt, undo scales (32 * 2048 = 65536) ----
__global__ void k_finish(const float* __restrict__ partial, float* __restrict__ out) {
  int b = blockIdx.x * 256 + threadIdx.x;
  float s = 0.f;
#pragma unroll
  for (int i = 0; i < 64; i++) s += partial[(size_t)i * B_DIM + b];
  out[b] = sqrtf(s) * (1.0f / 65536.0f);
}

extern "C" void kernel_launch(void* const* d_in, const int* in_sizes, int n_in,
                              void* d_out, int out_size, void* d_ws, size_t ws_size,
                              hipStream_t stream) {
  const float* x  = (const float*)d_in[0];
  const float* hw = (const float*)d_in[1];
  float* out = (float*)d_out;
  char* ws = (char*)d_ws;
  uint8_t* xq = (uint8_t*)ws;                                     // 32 MB
  uint8_t* wq = (uint8_t*)(ws + (size_t)B_DIM * K_DIM);           // 16 MB
  float* partial = (float*)(ws + (size_t)B_DIM * K_DIM
                               + (size_t)K_DIM * N_DIM);          // 2 MB
  long long R[3];
  mt_randint3(1367u, R);

  k_prep<<<8192 + 16384, 256, 0, stream>>>(x, xq, hw, wq, R[0], R[1], R[2]);
  k_gemm<<<(B_DIM / 256) * (N_DIM / 256), 512, 0, stream>>>(xq, wq, partial);
  k_finish<<<B_DIM / 256, 256, 0, stream>>>(partial, out);
}